// Round 1
// baseline (208.496 us; speedup 1.0000x reference)
//
#include <hip/hip_runtime.h>

#define D_M     64
#define L_OBS   256
#define ALPHA   256
#define D_H     256
#define D_V     64
#define N_HEADS 8

// ---------------------------------------------------------------------------
// Kernel 1: per-row imputation (scatter last-write-wins -> forward fill)
// grid = D_M blocks, 256 threads
// ---------------------------------------------------------------------------
__global__ __launch_bounds__(256) void impute_kernel(
    const float* __restrict__ x_ts, const float* __restrict__ t_ts,
    const float* __restrict__ gm, float* __restrict__ regular)
{
    const int m = blockIdx.x;
    const int l = threadIdx.x;
    __shared__ int   last[ALPHA];
    __shared__ float vals[ALPHA];
    __shared__ int   pos[ALPHA];

    last[l] = -1;
    __syncthreads();
    float x = x_ts[m * L_OBS + l];
    float t = t_ts[m * L_OBS + l];
    bool valid = (x == x) && (t >= 0.0f);
    int idx = (int)t;  // trunc toward zero == floor for t >= 0
    if (valid && idx < ALPHA) atomicMax(&last[idx], l);
    __syncthreads();
    int li = last[l];
    vals[l] = (li >= 0) ? x_ts[m * L_OBS + li] : 0.0f;
    pos[l]  = (li >= 0) ? l : -1;
    __syncthreads();
    // inclusive cummax scan (Hillis-Steele)
    for (int off = 1; off < ALPHA; off <<= 1) {
        int v = (l >= off) ? pos[l - off] : -1;
        __syncthreads();
        if (v > pos[l]) pos[l] = v;
        __syncthreads();
    }
    int lp = pos[l];
    regular[m * ALPHA + l] = (lp >= 0) ? vals[lp] : gm[m];
}

// ---------------------------------------------------------------------------
// Kernel 2: e_imp[a][h] = sum_m conv_w[h][m] * regular[m][a] + conv_b[h]
// grid = ALPHA blocks (a), 256 threads (h)
// ---------------------------------------------------------------------------
__global__ __launch_bounds__(256) void eimp_kernel(
    const float* __restrict__ conv_w, const float* __restrict__ conv_b,
    const float* __restrict__ regular, float* __restrict__ e_imp)
{
    const int a = blockIdx.x;
    const int tid = threadIdx.x;
    __shared__ float col[D_M];
    if (tid < D_M) col[tid] = regular[tid * ALPHA + a];
    __syncthreads();
    const float4* row = (const float4*)&conv_w[tid * D_M];
    const float4* c4  = (const float4*)col;
    float s0 = 0.f, s1 = 0.f, s2 = 0.f, s3 = 0.f;
    #pragma unroll
    for (int i = 0; i < D_M / 4; i++) {
        float4 r = row[i]; float4 c = c4[i];
        s0 += r.x * c.x; s1 += r.y * c.y; s2 += r.z * c.z; s3 += r.w * c.w;
    }
    e_imp[a * D_H + tid] = conv_b[tid] + ((s0 + s1) + (s2 + s3));
}

// ---------------------------------------------------------------------------
// Kernel 3: Q[h][a][e] = sum_d theta_a[h][a][d] * wq_w[h][e][d] + wq_b[h][e]
// grid = (ALPHA, N_HEADS), 64 threads (e)
// ---------------------------------------------------------------------------
__global__ __launch_bounds__(64) void q_kernel(
    const float* __restrict__ t2v_w, const float* __restrict__ t2v_phi,
    const float* __restrict__ wq_w, const float* __restrict__ wq_b,
    float* __restrict__ Qbuf)
{
    const int a = blockIdx.x;
    const int h = blockIdx.y;
    const int e = threadIdx.x;
    __shared__ float th[D_V];
    float f = t2v_w[h * D_V + e] * (float)a + t2v_phi[h * D_V + e];
    th[e] = (e == 0) ? f : sinf(f);
    __syncthreads();
    const float4* wrow = (const float4*)&wq_w[(h * D_V + e) * D_V];
    const float4* t4 = (const float4*)th;
    float s0 = 0.f, s1 = 0.f, s2 = 0.f, s3 = 0.f;
    #pragma unroll
    for (int i = 0; i < D_V / 4; i++) {
        float4 wv = wrow[i]; float4 tv = t4[i];
        s0 += tv.x * wv.x; s1 += tv.y * wv.y; s2 += tv.z * wv.z; s3 += tv.w * wv.w;
    }
    Qbuf[(h * ALPHA + a) * D_V + e] = wq_b[h * D_V + e] + ((s0 + s1) + (s2 + s3));
}

// ---------------------------------------------------------------------------
// Kernel 4: mTAND attention. One block per (m, h). 256 threads = 4 waves.
// Phase 1: K[l][e] into LDS (wave w computes row l0+w, lane = e).
// Phase 2: lane owns one a (a = 64*w + lane), Q in 64 VGPRs, online softmax
//          over l with K broadcast-read from LDS (conflict-free).
// ---------------------------------------------------------------------------
__global__ __launch_bounds__(256) void attn_kernel(
    const float* __restrict__ x_ts, const float* __restrict__ t_ts,
    const float* __restrict__ t2v_w, const float* __restrict__ t2v_phi,
    const float* __restrict__ wk_w, const float* __restrict__ wk_b,
    const float* __restrict__ Qbuf, float* __restrict__ interp)
{
    const int m   = blockIdx.x;
    const int h   = blockIdx.y;
    const int tid = threadIdx.x;
    const int w   = tid >> 6;
    const int ln  = tid & 63;

    __shared__ __align__(16) float K_s[L_OBS * D_V];   // 64 KiB, [l][e]
    __shared__ __align__(16) float theta_s[4 * D_V];
    __shared__ float x_s[L_OBS];
    __shared__ float msk_s[L_OBS];
    __shared__ float t_sh[L_OBS];

    {
        float x = x_ts[m * L_OBS + tid];
        float t = t_ts[m * L_OBS + tid];
        bool valid = (x == x) && (t >= 0.0f);
        x_s[tid]   = valid ? x : 0.0f;
        t_sh[tid]  = valid ? t : 0.0f;
        msk_s[tid] = valid ? 0.0f : -1e9f;  // additive mask; |score| << 1e9
    }

    // time2vec params for d = ln (phase 1 uses lane as d, then as e)
    const float wv = t2v_w[h * D_V + ln];
    const float pv = t2v_phi[h * D_V + ln];

    // preload wk_w[h][e=ln][:] into registers (invariant over l)
    float wk[D_V];
    {
        const float4* wp = (const float4*)&wk_w[(h * D_V + ln) * D_V];
        #pragma unroll
        for (int i = 0; i < D_V / 4; i++) {
            float4 v = wp[i];
            wk[4*i] = v.x; wk[4*i+1] = v.y; wk[4*i+2] = v.z; wk[4*i+3] = v.w;
        }
    }
    const float kb = wk_b[h * D_V + ln];
    __syncthreads();

    // ---- phase 1: K rows, 4 at a time (one per wave) ----
    for (int l0 = 0; l0 < L_OBS; l0 += 4) {
        float t = t_sh[l0 + w];
        float f = wv * t + pv;
        theta_s[w * D_V + ln] = (ln == 0) ? f : sinf(f);
        __syncthreads();
        const float4* th4 = (const float4*)&theta_s[w * D_V];
        float s0 = 0.f, s1 = 0.f, s2 = 0.f, s3 = 0.f;
        #pragma unroll
        for (int i = 0; i < D_V / 4; i++) {
            float4 tv = th4[i];
            s0 += tv.x * wk[4*i];   s1 += tv.y * wk[4*i+1];
            s2 += tv.z * wk[4*i+2]; s3 += tv.w * wk[4*i+3];
        }
        K_s[(l0 + w) * D_V + ln] = kb + ((s0 + s1) + (s2 + s3));
        __syncthreads();
    }

    // ---- phase 2: per-lane a, online softmax over l ----
    const int a = (w << 6) | ln;
    float q[D_V];
    {
        const float4* qp = (const float4*)&Qbuf[(h * ALPHA + a) * D_V];
        #pragma unroll
        for (int i = 0; i < D_V / 4; i++) {
            float4 v = qp[i];
            q[4*i] = v.x; q[4*i+1] = v.y; q[4*i+2] = v.z; q[4*i+3] = v.w;
        }
    }
    float mrun = -3.0e38f, ssum = 0.0f, acc = 0.0f;
    for (int l = 0; l < L_OBS; l++) {
        const float4* kp = (const float4*)&K_s[l * D_V];  // broadcast reads
        float s0 = 0.f, s1 = 0.f, s2 = 0.f, s3 = 0.f;
        #pragma unroll
        for (int i = 0; i < D_V / 4; i++) {
            float4 kv = kp[i];
            s0 += q[4*i]   * kv.x; s1 += q[4*i+1] * kv.y;
            s2 += q[4*i+2] * kv.z; s3 += q[4*i+3] * kv.w;
        }
        float s = ((s0 + s1) + (s2 + s3)) * 0.125f + msk_s[l];
        float mnew = fmaxf(mrun, s);
        float scl = __expf(mrun - mnew);
        float p   = __expf(s - mnew);
        ssum = ssum * scl + p;
        acc  = acc  * scl + p * x_s[l];
        mrun = mnew;
    }
    interp[(m * ALPHA + a) * N_HEADS + h] = acc / ssum;
}

// ---------------------------------------------------------------------------
// Kernel 5: e_attn[a][h'] = proj_b[h'] + (1/64) sum_{m,h} interp[m][a][h]*proj_w[h'][h]
// grid = ALPHA blocks, 256 threads (h')
// ---------------------------------------------------------------------------
__global__ __launch_bounds__(256) void eattn_kernel(
    const float* __restrict__ interp, const float* __restrict__ proj_w,
    const float* __restrict__ proj_b, float* __restrict__ e_attn)
{
    const int a = blockIdx.x;
    const int tid = threadIdx.x;
    __shared__ __align__(16) float sm[D_M * N_HEADS];  // 512
    for (int i = tid; i < D_M * N_HEADS; i += 256) {
        int mm = i >> 3, hh = i & 7;
        sm[i] = interp[(mm * ALPHA + a) * N_HEADS + hh];
    }
    __syncthreads();
    float pw[N_HEADS];
    {
        const float4* p4 = (const float4*)&proj_w[tid * N_HEADS];
        float4 v0 = p4[0], v1 = p4[1];
        pw[0] = v0.x; pw[1] = v0.y; pw[2] = v0.z; pw[3] = v0.w;
        pw[4] = v1.x; pw[5] = v1.y; pw[6] = v1.z; pw[7] = v1.w;
    }
    float sum = 0.0f;
    for (int mm = 0; mm < D_M; mm++) {
        const float4* s4 = (const float4*)&sm[mm * N_HEADS];
        float4 a0 = s4[0], a1 = s4[1];
        sum += a0.x * pw[0] + a0.y * pw[1] + a0.z * pw[2] + a0.w * pw[3]
             + a1.x * pw[4] + a1.y * pw[5] + a1.z * pw[6] + a1.w * pw[7];
    }
    e_attn[a * D_H + tid] = proj_b[tid] + sum * (1.0f / 64.0f);
}

// ---------------------------------------------------------------------------
// Kernel 6: gate MLP + output
// grid = ALPHA blocks (a), 256 threads
// ---------------------------------------------------------------------------
__global__ __launch_bounds__(256) void gate_kernel(
    const float* __restrict__ e_imp, const float* __restrict__ e_attn,
    const float* __restrict__ g1_w, const float* __restrict__ g1_b,
    const float* __restrict__ g2_w, const float* __restrict__ g2_b,
    float* __restrict__ out)
{
    const int a = blockIdx.x;
    const int tid = threadIdx.x;
    __shared__ __align__(16) float c_s[2 * D_H];
    __shared__ __align__(16) float h_s[D_H];
    c_s[tid]        = e_imp[a * D_H + tid];
    c_s[D_H + tid]  = e_attn[a * D_H + tid];
    __syncthreads();
    // hidden = relu(concat @ g1_w.T + g1_b)
    {
        const float4* grow = (const float4*)&g1_w[tid * 2 * D_H];
        const float4* c4 = (const float4*)c_s;
        float s0 = 0.f, s1 = 0.f, s2 = 0.f, s3 = 0.f;
        #pragma unroll 8
        for (int i = 0; i < (2 * D_H) / 4; i++) {
            float4 g = grow[i]; float4 c = c4[i];
            s0 += g.x * c.x; s1 += g.y * c.y; s2 += g.z * c.z; s3 += g.w * c.w;
        }
        float hid = g1_b[tid] + ((s0 + s1) + (s2 + s3));
        h_s[tid] = fmaxf(hid, 0.0f);
    }
    __syncthreads();
    {
        const float4* grow = (const float4*)&g2_w[tid * D_H];
        const float4* h4 = (const float4*)h_s;
        float s0 = 0.f, s1 = 0.f, s2 = 0.f, s3 = 0.f;
        #pragma unroll 8
        for (int i = 0; i < D_H / 4; i++) {
            float4 g = grow[i]; float4 hh = h4[i];
            s0 += g.x * hh.x; s1 += g.y * hh.y; s2 += g.z * hh.z; s3 += g.w * hh.w;
        }
        float z = g2_b[tid] + ((s0 + s1) + (s2 + s3));
        float gate = 1.0f / (1.0f + __expf(-z));
        out[a * D_H + tid] = gate * c_s[tid] + (1.0f - gate) * c_s[D_H + tid];
    }
}

// ---------------------------------------------------------------------------
extern "C" void kernel_launch(void* const* d_in, const int* in_sizes, int n_in,
                              void* d_out, int out_size, void* d_ws, size_t ws_size,
                              hipStream_t stream)
{
    (void)in_sizes; (void)n_in; (void)out_size; (void)ws_size;

    const float* x_ts    = (const float*)d_in[0];
    const float* t_ts    = (const float*)d_in[1];
    const float* gm      = (const float*)d_in[2];
    const float* conv_w  = (const float*)d_in[3];
    const float* conv_b  = (const float*)d_in[4];
    const float* t2v_w   = (const float*)d_in[5];
    const float* t2v_phi = (const float*)d_in[6];
    const float* wq_w    = (const float*)d_in[7];
    const float* wq_b    = (const float*)d_in[8];
    const float* wk_w    = (const float*)d_in[9];
    const float* wk_b    = (const float*)d_in[10];
    const float* proj_w  = (const float*)d_in[11];
    const float* proj_b  = (const float*)d_in[12];
    const float* g1_w    = (const float*)d_in[13];
    const float* g1_b    = (const float*)d_in[14];
    const float* g2_w    = (const float*)d_in[15];
    const float* g2_b    = (const float*)d_in[16];

    float* out = (float*)d_out;

    float* ws      = (float*)d_ws;
    float* regular = ws;                       // D_M*ALPHA        = 16384
    float* e_imp   = regular + D_M * ALPHA;    // ALPHA*D_H        = 65536
    float* Qbuf    = e_imp + ALPHA * D_H;      // H*ALPHA*D_V      = 131072
    float* interp  = Qbuf + N_HEADS * ALPHA * D_V;  // D_M*ALPHA*H = 131072
    float* e_attn  = interp + D_M * ALPHA * N_HEADS; // ALPHA*D_H  = 65536

    impute_kernel<<<D_M, 256, 0, stream>>>(x_ts, t_ts, gm, regular);
    eimp_kernel<<<ALPHA, 256, 0, stream>>>(conv_w, conv_b, regular, e_imp);
    q_kernel<<<dim3(ALPHA, N_HEADS), 64, 0, stream>>>(t2v_w, t2v_phi, wq_w, wq_b, Qbuf);
    attn_kernel<<<dim3(D_M, N_HEADS), 256, 0, stream>>>(
        x_ts, t_ts, t2v_w, t2v_phi, wk_w, wk_b, Qbuf, interp);
    eattn_kernel<<<ALPHA, 256, 0, stream>>>(interp, proj_w, proj_b, e_attn);
    gate_kernel<<<ALPHA, 256, 0, stream>>>(e_imp, e_attn, g1_w, g1_b, g2_w, g2_b, out);
}

// Round 2
// 133.879 us; speedup vs baseline: 1.5574x; 1.5574x over previous
//
#include <hip/hip_runtime.h>

#define D_M     64
#define L_OBS   256
#define ALPHA   256
#define D_H     256
#define D_V     64
#define N_HEADS 8

// ---------------------------------------------------------------------------
// Kernel 1: per-row imputation (scatter last-write-wins -> forward fill)
// ---------------------------------------------------------------------------
__global__ __launch_bounds__(256) void impute_kernel(
    const float* __restrict__ x_ts, const float* __restrict__ t_ts,
    const float* __restrict__ gm, float* __restrict__ regular)
{
    const int m = blockIdx.x;
    const int l = threadIdx.x;
    __shared__ int   last[ALPHA];
    __shared__ float vals[ALPHA];
    __shared__ int   pos[ALPHA];

    last[l] = -1;
    __syncthreads();
    float x = x_ts[m * L_OBS + l];
    float t = t_ts[m * L_OBS + l];
    bool valid = (x == x) && (t >= 0.0f);
    int idx = (int)t;
    if (valid && idx < ALPHA) atomicMax(&last[idx], l);
    __syncthreads();
    int li = last[l];
    vals[l] = (li >= 0) ? x_ts[m * L_OBS + li] : 0.0f;
    pos[l]  = (li >= 0) ? l : -1;
    __syncthreads();
    for (int off = 1; off < ALPHA; off <<= 1) {
        int v = (l >= off) ? pos[l - off] : -1;
        __syncthreads();
        if (v > pos[l]) pos[l] = v;
        __syncthreads();
    }
    int lp = pos[l];
    regular[m * ALPHA + l] = (lp >= 0) ? vals[lp] : gm[m];
}

// ---------------------------------------------------------------------------
// Kernel 2: e_imp[a][h] = sum_m conv_w[h][m] * regular[m][a] + conv_b[h]
// ---------------------------------------------------------------------------
__global__ __launch_bounds__(256) void eimp_kernel(
    const float* __restrict__ conv_w, const float* __restrict__ conv_b,
    const float* __restrict__ regular, float* __restrict__ e_imp)
{
    const int a = blockIdx.x;
    const int tid = threadIdx.x;
    __shared__ float col[D_M];
    if (tid < D_M) col[tid] = regular[tid * ALPHA + a];
    __syncthreads();
    const float4* row = (const float4*)&conv_w[tid * D_M];
    const float4* c4  = (const float4*)col;
    float s0 = 0.f, s1 = 0.f, s2 = 0.f, s3 = 0.f;
    #pragma unroll
    for (int i = 0; i < D_M / 4; i++) {
        float4 r = row[i]; float4 c = c4[i];
        s0 += r.x * c.x; s1 += r.y * c.y; s2 += r.z * c.z; s3 += r.w * c.w;
    }
    e_imp[a * D_H + tid] = conv_b[tid] + ((s0 + s1) + (s2 + s3));
}

// ---------------------------------------------------------------------------
// Kernel 3: QbufT[h][e][a] = sum_d theta_a[h][a][d]*wq_w[h][e][d] + wq_b[h][e]
// (transposed layout for the attn kernel's per-e row reads)
// ---------------------------------------------------------------------------
__global__ __launch_bounds__(64) void qT_kernel(
    const float* __restrict__ t2v_w, const float* __restrict__ t2v_phi,
    const float* __restrict__ wq_w, const float* __restrict__ wq_b,
    float* __restrict__ QbufT)
{
    const int a = blockIdx.x;
    const int h = blockIdx.y;
    const int e = threadIdx.x;
    __shared__ float th[D_V];
    float f = t2v_w[h * D_V + e] * (float)a + t2v_phi[h * D_V + e];
    th[e] = (e == 0) ? f : __sinf(f);
    __syncthreads();
    const float4* wrow = (const float4*)&wq_w[(h * D_V + e) * D_V];
    const float4* t4 = (const float4*)th;
    float s0 = 0.f, s1 = 0.f, s2 = 0.f, s3 = 0.f;
    #pragma unroll
    for (int i = 0; i < D_V / 4; i++) {
        float4 wv = wrow[i]; float4 tv = t4[i];
        s0 += tv.x * wv.x; s1 += tv.y * wv.y; s2 += tv.z * wv.z; s3 += tv.w * wv.w;
    }
    QbufT[(h * D_V + e) * ALPHA + a] =
        wq_b[h * D_V + e] + ((s0 + s1) + (s2 + s3));
}

// ---------------------------------------------------------------------------
// Kernel 4: fused mTAND attention, register-tiled.
// Block per (m,h), 256 threads. Per 64-l tile:
//   P1: theta[d][l] into LDS (64x64)
//   P2: K[e][l] = wk . theta  (thread tile 4e x 4l, operands from LDS)
//   P3: scores  = Q . K       (thread tile 8a x 8l; Q from global/L2,
//                              K from LDS; 4 loads per 64 FMA)
//   online softmax per a-row, reduced over 8 tl-lanes via shfl_xor
// LDS read patterns are <=2-way per bank with broadcast (free).
// ---------------------------------------------------------------------------
__global__ __launch_bounds__(256) void attn_fused_kernel(
    const float* __restrict__ x_ts, const float* __restrict__ t_ts,
    const float* __restrict__ t2v_w, const float* __restrict__ t2v_phi,
    const float* __restrict__ wk_w, const float* __restrict__ wk_b,
    const float* __restrict__ QbufT, float* __restrict__ interp)
{
    const int m   = blockIdx.x;
    const int h   = blockIdx.y;
    const int tid = threadIdx.x;

    __shared__ __align__(16) float wkt[D_V][D_V];   // [d][e] 16 KiB
    __shared__ __align__(16) float tht[D_V][64];    // [d][l] 16 KiB
    __shared__ __align__(16) float Kt [D_V][64];    // [e][l] 16 KiB
    __shared__ float x_s[L_OBS];
    __shared__ float t_sh[L_OBS];
    __shared__ float msk_s[L_OBS];

    {
        float x = x_ts[m * L_OBS + tid];
        float t = t_ts[m * L_OBS + tid];
        bool v = (x == x) && (t >= 0.0f);
        x_s[tid]   = v ? x : 0.0f;
        t_sh[tid]  = v ? t : 0.0f;
        msk_s[tid] = v ? 0.0f : -1e9f;
    }
    // stage wk transposed: wkt[d][e] <- wk_w[h][e][d]
    {
        const float4* w4 = (const float4*)(wk_w + h * D_V * D_V);
        #pragma unroll
        for (int i = 0; i < 4; i++) {
            int f = i * 256 + tid;       // float4 index into [e][d]
            float4 v = w4[f];
            int e  = f >> 4;             // 16 float4 per e-row
            int db = (f & 15) * 4;
            wkt[db + 0][e] = v.x; wkt[db + 1][e] = v.y;
            wkt[db + 2][e] = v.z; wkt[db + 3][e] = v.w;
        }
    }

    const int ta  = tid >> 3;   // P3: 32 groups x 8 a
    const int tl  = tid & 7;    // P3: 8 groups x 8 l
    const int te  = tid >> 4;   // P2: 16 groups x 4 e
    const int tl4 = tid & 15;   // P2: 16 groups x 4 l

    float mrun[8], ssum[8], axs[8];
    #pragma unroll
    for (int i = 0; i < 8; i++) { mrun[i] = -3.0e38f; ssum[i] = 0.f; axs[i] = 0.f; }

    const float4* QT4 = (const float4*)(QbufT + h * D_V * ALPHA); // row e: 64 float4

    for (int tt = 0; tt < 4; tt++) {
        __syncthreads();   // previous tile's tht/Kt readers done
        // ---- P1: theta tile ----
        {
            int lloc = tid & 63;
            float tval = t_sh[tt * 64 + lloc];
            int d0 = (tid >> 6) * 16;
            #pragma unroll
            for (int dd = 0; dd < 16; dd++) {
                int d = d0 + dd;
                float f = t2v_w[h * D_V + d] * tval + t2v_phi[h * D_V + d];
                tht[d][lloc] = (d == 0) ? f : __sinf(f);
            }
        }
        __syncthreads();
        // ---- P2: K projection (4e x 4l per thread) ----
        {
            float ka[4][4];
            #pragma unroll
            for (int i = 0; i < 4; i++)
                #pragma unroll
                for (int j = 0; j < 4; j++) ka[i][j] = 0.f;
            #pragma unroll 8
            for (int d = 0; d < D_V; d++) {
                float4 wv = *(const float4*)&wkt[d][te * 4];
                float4 th = *(const float4*)&tht[d][tl4 * 4];
                float wa[4] = {wv.x, wv.y, wv.z, wv.w};
                float tb[4] = {th.x, th.y, th.z, th.w};
                #pragma unroll
                for (int i = 0; i < 4; i++)
                    #pragma unroll
                    for (int j = 0; j < 4; j++)
                        ka[i][j] = fmaf(wa[i], tb[j], ka[i][j]);
            }
            #pragma unroll
            for (int i = 0; i < 4; i++) {
                float b = wk_b[h * D_V + te * 4 + i];
                float4 o;
                o.x = ka[i][0] + b; o.y = ka[i][1] + b;
                o.z = ka[i][2] + b; o.w = ka[i][3] + b;
                *(float4*)&Kt[te * 4 + i][tl4 * 4] = o;
            }
        }
        __syncthreads();
        // ---- P3: QK^T (8a x 8l per thread) ----
        float acc[8][8];
        #pragma unroll
        for (int i = 0; i < 8; i++)
            #pragma unroll
            for (int j = 0; j < 8; j++) acc[i][j] = 0.f;
        #pragma unroll 4
        for (int e = 0; e < D_V; e++) {
            float4 q0 = QT4[e * 64 + ta * 2];
            float4 q1 = QT4[e * 64 + ta * 2 + 1];
            float4 k0 = *(const float4*)&Kt[e][tl * 8];
            float4 k1 = *(const float4*)&Kt[e][tl * 8 + 4];
            float qa[8] = {q0.x, q0.y, q0.z, q0.w, q1.x, q1.y, q1.z, q1.w};
            float kb[8] = {k0.x, k0.y, k0.z, k0.w, k1.x, k1.y, k1.z, k1.w};
            #pragma unroll
            for (int i = 0; i < 8; i++)
                #pragma unroll
                for (int j = 0; j < 8; j++)
                    acc[i][j] = fmaf(qa[i], kb[j], acc[i][j]);
        }
        // ---- online softmax update ----
        float xv[8], mk[8];
        {
            int lb = tt * 64 + tl * 8;
            float4 a0 = *(const float4*)&x_s[lb];
            float4 a1 = *(const float4*)&x_s[lb + 4];
            float4 m0 = *(const float4*)&msk_s[lb];
            float4 m1 = *(const float4*)&msk_s[lb + 4];
            xv[0]=a0.x; xv[1]=a0.y; xv[2]=a0.z; xv[3]=a0.w;
            xv[4]=a1.x; xv[5]=a1.y; xv[6]=a1.z; xv[7]=a1.w;
            mk[0]=m0.x; mk[1]=m0.y; mk[2]=m0.z; mk[3]=m0.w;
            mk[4]=m1.x; mk[5]=m1.y; mk[6]=m1.z; mk[7]=m1.w;
        }
        #pragma unroll
        for (int i = 0; i < 8; i++) {
            float s[8];
            #pragma unroll
            for (int j = 0; j < 8; j++) s[j] = fmaf(acc[i][j], 0.125f, mk[j]);
            float tmax = s[0];
            #pragma unroll
            for (int j = 1; j < 8; j++) tmax = fmaxf(tmax, s[j]);
            tmax = fmaxf(tmax, __shfl_xor(tmax, 1));
            tmax = fmaxf(tmax, __shfl_xor(tmax, 2));
            tmax = fmaxf(tmax, __shfl_xor(tmax, 4));
            float mnew = fmaxf(mrun[i], tmax);
            float scl = __expf(mrun[i] - mnew);
            float ps = 0.f, px = 0.f;
            #pragma unroll
            for (int j = 0; j < 8; j++) {
                float p = __expf(s[j] - mnew);
                ps += p;
                px = fmaf(p, xv[j], px);
            }
            ps += __shfl_xor(ps, 1); px += __shfl_xor(px, 1);
            ps += __shfl_xor(ps, 2); px += __shfl_xor(px, 2);
            ps += __shfl_xor(ps, 4); px += __shfl_xor(px, 4);
            ssum[i] = fmaf(ssum[i], scl, ps);
            axs[i]  = fmaf(axs[i],  scl, px);
            mrun[i] = mnew;
        }
    }

    if (tl == 0) {
        #pragma unroll
        for (int i = 0; i < 8; i++)
            interp[(m * ALPHA + (ta * 8 + i)) * N_HEADS + h] = axs[i] / ssum[i];
    }
}

// ---------------------------------------------------------------------------
// Kernel 5: e_attn[a][h'] = proj_b[h'] + (1/64) sum_{m,h} interp[m][a][h]*proj_w[h'][h]
// ---------------------------------------------------------------------------
__global__ __launch_bounds__(256) void eattn_kernel(
    const float* __restrict__ interp, const float* __restrict__ proj_w,
    const float* __restrict__ proj_b, float* __restrict__ e_attn)
{
    const int a = blockIdx.x;
    const int tid = threadIdx.x;
    __shared__ __align__(16) float sm[D_M * N_HEADS];
    for (int i = tid; i < D_M * N_HEADS; i += 256) {
        int mm = i >> 3, hh = i & 7;
        sm[i] = interp[(mm * ALPHA + a) * N_HEADS + hh];
    }
    __syncthreads();
    float pw[N_HEADS];
    {
        const float4* p4 = (const float4*)&proj_w[tid * N_HEADS];
        float4 v0 = p4[0], v1 = p4[1];
        pw[0] = v0.x; pw[1] = v0.y; pw[2] = v0.z; pw[3] = v0.w;
        pw[4] = v1.x; pw[5] = v1.y; pw[6] = v1.z; pw[7] = v1.w;
    }
    float sum = 0.0f;
    for (int mm = 0; mm < D_M; mm++) {
        const float4* s4 = (const float4*)&sm[mm * N_HEADS];
        float4 a0 = s4[0], a1 = s4[1];
        sum += a0.x * pw[0] + a0.y * pw[1] + a0.z * pw[2] + a0.w * pw[3]
             + a1.x * pw[4] + a1.y * pw[5] + a1.z * pw[6] + a1.w * pw[7];
    }
    e_attn[a * D_H + tid] = proj_b[tid] + sum * (1.0f / 64.0f);
}

// ---------------------------------------------------------------------------
// Kernel 6: gate MLP + output
// ---------------------------------------------------------------------------
__global__ __launch_bounds__(256) void gate_kernel(
    const float* __restrict__ e_imp, const float* __restrict__ e_attn,
    const float* __restrict__ g1_w, const float* __restrict__ g1_b,
    const float* __restrict__ g2_w, const float* __restrict__ g2_b,
    float* __restrict__ out)
{
    const int a = blockIdx.x;
    const int tid = threadIdx.x;
    __shared__ __align__(16) float c_s[2 * D_H];
    __shared__ __align__(16) float h_s[D_H];
    c_s[tid]        = e_imp[a * D_H + tid];
    c_s[D_H + tid]  = e_attn[a * D_H + tid];
    __syncthreads();
    {
        const float4* grow = (const float4*)&g1_w[tid * 2 * D_H];
        const float4* c4 = (const float4*)c_s;
        float s0 = 0.f, s1 = 0.f, s2 = 0.f, s3 = 0.f;
        #pragma unroll 8
        for (int i = 0; i < (2 * D_H) / 4; i++) {
            float4 g = grow[i]; float4 c = c4[i];
            s0 += g.x * c.x; s1 += g.y * c.y; s2 += g.z * c.z; s3 += g.w * c.w;
        }
        float hid = g1_b[tid] + ((s0 + s1) + (s2 + s3));
        h_s[tid] = fmaxf(hid, 0.0f);
    }
    __syncthreads();
    {
        const float4* grow = (const float4*)&g2_w[tid * D_H];
        const float4* h4 = (const float4*)h_s;
        float s0 = 0.f, s1 = 0.f, s2 = 0.f, s3 = 0.f;
        #pragma unroll 8
        for (int i = 0; i < D_H / 4; i++) {
            float4 g = grow[i]; float4 hh = h4[i];
            s0 += g.x * hh.x; s1 += g.y * hh.y; s2 += g.z * hh.z; s3 += g.w * hh.w;
        }
        float z = g2_b[tid] + ((s0 + s1) + (s2 + s3));
        float gate = 1.0f / (1.0f + __expf(-z));
        out[a * D_H + tid] = gate * c_s[tid] + (1.0f - gate) * c_s[D_H + tid];
    }
}

// ---------------------------------------------------------------------------
extern "C" void kernel_launch(void* const* d_in, const int* in_sizes, int n_in,
                              void* d_out, int out_size, void* d_ws, size_t ws_size,
                              hipStream_t stream)
{
    (void)in_sizes; (void)n_in; (void)out_size; (void)ws_size;

    const float* x_ts    = (const float*)d_in[0];
    const float* t_ts    = (const float*)d_in[1];
    const float* gm      = (const float*)d_in[2];
    const float* conv_w  = (const float*)d_in[3];
    const float* conv_b  = (const float*)d_in[4];
    const float* t2v_w   = (const float*)d_in[5];
    const float* t2v_phi = (const float*)d_in[6];
    const float* wq_w    = (const float*)d_in[7];
    const float* wq_b    = (const float*)d_in[8];
    const float* wk_w    = (const float*)d_in[9];
    const float* wk_b    = (const float*)d_in[10];
    const float* proj_w  = (const float*)d_in[11];
    const float* proj_b  = (const float*)d_in[12];
    const float* g1_w    = (const float*)d_in[13];
    const float* g1_b    = (const float*)d_in[14];
    const float* g2_w    = (const float*)d_in[15];
    const float* g2_b    = (const float*)d_in[16];

    float* out = (float*)d_out;

    float* ws      = (float*)d_ws;
    float* regular = ws;                              // 16384
    float* e_imp   = regular + D_M * ALPHA;           // 65536
    float* QbufT   = e_imp + ALPHA * D_H;             // 131072
    float* interp  = QbufT + N_HEADS * D_V * ALPHA;   // 131072
    float* e_attn  = interp + D_M * ALPHA * N_HEADS;  // 65536

    impute_kernel<<<D_M, 256, 0, stream>>>(x_ts, t_ts, gm, regular);
    eimp_kernel<<<ALPHA, 256, 0, stream>>>(conv_w, conv_b, regular, e_imp);
    qT_kernel<<<dim3(ALPHA, N_HEADS), 64, 0, stream>>>(t2v_w, t2v_phi, wq_w, wq_b, QbufT);
    attn_fused_kernel<<<dim3(D_M, N_HEADS), 256, 0, stream>>>(
        x_ts, t_ts, t2v_w, t2v_phi, wk_w, wk_b, QbufT, interp);
    eattn_kernel<<<ALPHA, 256, 0, stream>>>(interp, proj_w, proj_b, e_attn);
    gate_kernel<<<ALPHA, 256, 0, stream>>>(e_imp, e_attn, g1_w, g1_b, g2_w, g2_b, out);
}

// Round 3
// 116.291 us; speedup vs baseline: 1.7929x; 1.1512x over previous
//
#include <hip/hip_runtime.h>

#define D_M     64
#define L_OBS   256
#define ALPHA   256
#define D_H     256
#define D_V     64
#define N_HEADS 8

// ---------------------------------------------------------------------------
// Kernel 1: per-row imputation (scatter last-write-wins -> forward fill)
// ---------------------------------------------------------------------------
__global__ __launch_bounds__(256) void impute_kernel(
    const float* __restrict__ x_ts, const float* __restrict__ t_ts,
    const float* __restrict__ gm, float* __restrict__ regular)
{
    const int m = blockIdx.x;
    const int l = threadIdx.x;
    __shared__ int   last[ALPHA];
    __shared__ float vals[ALPHA];
    __shared__ int   pos[ALPHA];

    last[l] = -1;
    __syncthreads();
    float x = x_ts[m * L_OBS + l];
    float t = t_ts[m * L_OBS + l];
    bool valid = (x == x) && (t >= 0.0f);
    int idx = (int)t;
    if (valid && idx < ALPHA) atomicMax(&last[idx], l);
    __syncthreads();
    int li = last[l];
    vals[l] = (li >= 0) ? x_ts[m * L_OBS + li] : 0.0f;
    pos[l]  = (li >= 0) ? l : -1;
    __syncthreads();
    for (int off = 1; off < ALPHA; off <<= 1) {
        int v = (l >= off) ? pos[l - off] : -1;
        __syncthreads();
        if (v > pos[l]) pos[l] = v;
        __syncthreads();
    }
    int lp = pos[l];
    regular[m * ALPHA + l] = (lp >= 0) ? vals[lp] : gm[m];
}

// ---------------------------------------------------------------------------
// Kernel 2: QbufT[h][e][a] = sum_d theta_a[h][a][d]*wq_w[h][e][d] + wq_b[h][e]
// ---------------------------------------------------------------------------
__global__ __launch_bounds__(64) void qT_kernel(
    const float* __restrict__ t2v_w, const float* __restrict__ t2v_phi,
    const float* __restrict__ wq_w, const float* __restrict__ wq_b,
    float* __restrict__ QbufT)
{
    const int a = blockIdx.x;
    const int h = blockIdx.y;
    const int e = threadIdx.x;
    __shared__ float th[D_V];
    float f = t2v_w[h * D_V + e] * (float)a + t2v_phi[h * D_V + e];
    th[e] = (e == 0) ? f : __sinf(f);
    __syncthreads();
    const float4* wrow = (const float4*)&wq_w[(h * D_V + e) * D_V];
    const float4* t4 = (const float4*)th;
    float s0 = 0.f, s1 = 0.f, s2 = 0.f, s3 = 0.f;
    #pragma unroll
    for (int i = 0; i < D_V / 4; i++) {
        float4 wv = wrow[i]; float4 tv = t4[i];
        s0 += tv.x * wv.x; s1 += tv.y * wv.y; s2 += tv.z * wv.z; s3 += tv.w * wv.w;
    }
    QbufT[(h * D_V + e) * ALPHA + a] =
        wq_b[h * D_V + e] + ((s0 + s1) + (s2 + s3));
}

// ---------------------------------------------------------------------------
// Kernel 3: fused mTAND attention. Block = 512 threads = (2 m) x (256 thr),
// grid = (D_M/2, N_HEADS) = 256 blocks = exactly 1 per CU.
// Q for this head lives entirely in LDS (staged once from L2).
// Per 64-l tile (per m-half):
//   P1: theta[d][l] -> LDS ; P2: K[e][l] = wkt . theta (4e x 4l/thread)
//   P3: scores = Qs . Kt (8a x 8l/thread, both operands LDS, zero global)
//   online softmax per a-row over 8 tl lanes (shfl_xor)
// LDS: Qs 64K + wkt 16K + tht 32K + Kt 32K + x/t/msk 6K = 150 KiB.
// ---------------------------------------------------------------------------
__global__ __launch_bounds__(512) void attn_fused_kernel(
    const float* __restrict__ x_ts, const float* __restrict__ t_ts,
    const float* __restrict__ t2v_w, const float* __restrict__ t2v_phi,
    const float* __restrict__ wk_w, const float* __restrict__ wk_b,
    const float* __restrict__ QbufT, float* __restrict__ interp)
{
    const int mp  = blockIdx.x;     // m pair
    const int h   = blockIdx.y;
    const int tid = threadIdx.x;    // 0..511
    const int hm  = tid >> 8;       // which m of the pair (wave-aligned)
    const int t2  = tid & 255;
    const int m   = mp * 2 + hm;

    __shared__ __align__(16) float Qs[D_V][ALPHA];    // 64 KiB [e][a]
    __shared__ __align__(16) float wkt[D_V][D_V];     // 16 KiB [d][e]
    __shared__ __align__(16) float tht[2][D_V][64];   // 32 KiB [hm][d][l]
    __shared__ __align__(16) float Kt [2][D_V][64];   // 32 KiB [hm][e][l]
    __shared__ float x_s[2][L_OBS];
    __shared__ float t_sh[2][L_OBS];
    __shared__ float msk_s[2][L_OBS];

    // ---- stage obs row for this half's m ----
    {
        float x = x_ts[m * L_OBS + t2];
        float t = t_ts[m * L_OBS + t2];
        bool v = (x == x) && (t >= 0.0f);
        x_s[hm][t2]   = v ? x : 0.0f;
        t_sh[hm][t2]  = v ? t : 0.0f;
        msk_s[hm][t2] = v ? 0.0f : -1e9f;
    }
    // ---- stage wk transposed: wkt[d][e] <- wk_w[h][e][d] (1024 float4) ----
    {
        const float4* w4 = (const float4*)(wk_w + h * D_V * D_V);
        #pragma unroll
        for (int i = 0; i < 2; i++) {
            int f = i * 512 + tid;
            float4 v = w4[f];
            int e  = f >> 4;
            int db = (f & 15) * 4;
            wkt[db + 0][e] = v.x; wkt[db + 1][e] = v.y;
            wkt[db + 2][e] = v.z; wkt[db + 3][e] = v.w;
        }
    }
    // ---- stage Q row [e][a], same linear layout as QbufT row (4096 float4) ----
    {
        const float4* q4 = (const float4*)(QbufT + h * D_V * ALPHA);
        float4* qs4 = (float4*)&Qs[0][0];
        #pragma unroll
        for (int i = 0; i < 8; i++)
            qs4[i * 512 + tid] = q4[i * 512 + tid];
    }

    // hoist time2vec params for this thread's d-range (P1)
    const int d0 = (t2 >> 6) * 16;
    float wreg[16], preg[16];
    {
        const float4* wp = (const float4*)&t2v_w[h * D_V + d0];
        const float4* pp = (const float4*)&t2v_phi[h * D_V + d0];
        #pragma unroll
        for (int i = 0; i < 4; i++) {
            float4 wv = wp[i], pv = pp[i];
            wreg[4*i] = wv.x; wreg[4*i+1] = wv.y; wreg[4*i+2] = wv.z; wreg[4*i+3] = wv.w;
            preg[4*i] = pv.x; preg[4*i+1] = pv.y; preg[4*i+2] = pv.z; preg[4*i+3] = pv.w;
        }
    }
    const int te  = t2 >> 4;    // P2: 16 groups x 4 e
    const int tl4 = t2 & 15;    // P2: 16 groups x 4 l
    float kb4[4];
    {
        const float4* b4 = (const float4*)&wk_b[h * D_V + te * 4];
        float4 v = b4[0];
        kb4[0] = v.x; kb4[1] = v.y; kb4[2] = v.z; kb4[3] = v.w;
    }
    const int ta = t2 >> 3;     // P3: 32 groups x 8 a
    const int tl = t2 & 7;      // P3: 8 groups x 8 l

    float mrun[8], ssum[8], axs[8];
    #pragma unroll
    for (int i = 0; i < 8; i++) { mrun[i] = -3.0e38f; ssum[i] = 0.f; axs[i] = 0.f; }

    __syncthreads();   // staging (x, wkt, Qs) complete

    for (int tt = 0; tt < 4; tt++) {
        // ---- P1: theta tile for this half's m ----
        {
            int lloc = t2 & 63;
            float tval = t_sh[hm][tt * 64 + lloc];
            #pragma unroll
            for (int dd = 0; dd < 16; dd++) {
                int d = d0 + dd;
                float f = wreg[dd] * tval + preg[dd];
                tht[hm][d][lloc] = (d == 0) ? f : __sinf(f);
            }
        }
        __syncthreads();   // tht ready; also: everyone done reading prev Kt
        // ---- P2: K projection (4e x 4l per thread) ----
        {
            float ka[4][4];
            #pragma unroll
            for (int i = 0; i < 4; i++)
                #pragma unroll
                for (int j = 0; j < 4; j++) ka[i][j] = 0.f;
            #pragma unroll 8
            for (int d = 0; d < D_V; d++) {
                float4 wv = *(const float4*)&wkt[d][te * 4];
                float4 th = *(const float4*)&tht[hm][d][tl4 * 4];
                float wa[4] = {wv.x, wv.y, wv.z, wv.w};
                float tb[4] = {th.x, th.y, th.z, th.w};
                #pragma unroll
                for (int i = 0; i < 4; i++)
                    #pragma unroll
                    for (int j = 0; j < 4; j++)
                        ka[i][j] = fmaf(wa[i], tb[j], ka[i][j]);
            }
            #pragma unroll
            for (int i = 0; i < 4; i++) {
                float4 o;
                o.x = ka[i][0] + kb4[i]; o.y = ka[i][1] + kb4[i];
                o.z = ka[i][2] + kb4[i]; o.w = ka[i][3] + kb4[i];
                *(float4*)&Kt[hm][te * 4 + i][tl4 * 4] = o;
            }
        }
        __syncthreads();   // Kt ready
        // ---- P3: QK^T (8a x 8l per thread), all-LDS operands ----
        float acc[8][8];
        #pragma unroll
        for (int i = 0; i < 8; i++)
            #pragma unroll
            for (int j = 0; j < 8; j++) acc[i][j] = 0.f;
        #pragma unroll 4
        for (int e = 0; e < D_V; e++) {
            float4 q0 = *(const float4*)&Qs[e][ta * 8];
            float4 q1 = *(const float4*)&Qs[e][ta * 8 + 4];
            float4 k0 = *(const float4*)&Kt[hm][e][tl * 8];
            float4 k1 = *(const float4*)&Kt[hm][e][tl * 8 + 4];
            float qa[8] = {q0.x, q0.y, q0.z, q0.w, q1.x, q1.y, q1.z, q1.w};
            float kb[8] = {k0.x, k0.y, k0.z, k0.w, k1.x, k1.y, k1.z, k1.w};
            #pragma unroll
            for (int i = 0; i < 8; i++)
                #pragma unroll
                for (int j = 0; j < 8; j++)
                    acc[i][j] = fmaf(qa[i], kb[j], acc[i][j]);
        }
        // ---- online softmax update ----
        float xv[8], mk[8];
        {
            int lb = tt * 64 + tl * 8;
            float4 a0 = *(const float4*)&x_s[hm][lb];
            float4 a1 = *(const float4*)&x_s[hm][lb + 4];
            float4 m0 = *(const float4*)&msk_s[hm][lb];
            float4 m1 = *(const float4*)&msk_s[hm][lb + 4];
            xv[0]=a0.x; xv[1]=a0.y; xv[2]=a0.z; xv[3]=a0.w;
            xv[4]=a1.x; xv[5]=a1.y; xv[6]=a1.z; xv[7]=a1.w;
            mk[0]=m0.x; mk[1]=m0.y; mk[2]=m0.z; mk[3]=m0.w;
            mk[4]=m1.x; mk[5]=m1.y; mk[6]=m1.z; mk[7]=m1.w;
        }
        #pragma unroll
        for (int i = 0; i < 8; i++) {
            float s[8];
            #pragma unroll
            for (int j = 0; j < 8; j++) s[j] = fmaf(acc[i][j], 0.125f, mk[j]);
            float tmax = s[0];
            #pragma unroll
            for (int j = 1; j < 8; j++) tmax = fmaxf(tmax, s[j]);
            tmax = fmaxf(tmax, __shfl_xor(tmax, 1));
            tmax = fmaxf(tmax, __shfl_xor(tmax, 2));
            tmax = fmaxf(tmax, __shfl_xor(tmax, 4));
            float mnew = fmaxf(mrun[i], tmax);
            float scl = __expf(mrun[i] - mnew);
            float ps = 0.f, px = 0.f;
            #pragma unroll
            for (int j = 0; j < 8; j++) {
                float p = __expf(s[j] - mnew);
                ps += p;
                px = fmaf(p, xv[j], px);
            }
            ps += __shfl_xor(ps, 1); px += __shfl_xor(px, 1);
            ps += __shfl_xor(ps, 2); px += __shfl_xor(px, 2);
            ps += __shfl_xor(ps, 4); px += __shfl_xor(px, 4);
            ssum[i] = fmaf(ssum[i], scl, ps);
            axs[i]  = fmaf(axs[i],  scl, px);
            mrun[i] = mnew;
        }
        if (tt < 3) __syncthreads();  // allow next tile's P1 (tht) overwrite guard
    }

    // interp layout [a][m][h] so the final kernel reads contiguously
    if (tl == 0) {
        #pragma unroll
        for (int i = 0; i < 8; i++)
            interp[(ta * 8 + i) * (D_M * N_HEADS) + m * N_HEADS + h] =
                axs[i] / ssum[i];
    }
}

// ---------------------------------------------------------------------------
// Kernel 4: fused e_imp + e_attn + gate MLP + output. Block per a, 256 thr.
// ---------------------------------------------------------------------------
__global__ __launch_bounds__(256) void final_kernel(
    const float* __restrict__ regular, const float* __restrict__ interp,
    const float* __restrict__ conv_w, const float* __restrict__ conv_b,
    const float* __restrict__ proj_w, const float* __restrict__ proj_b,
    const float* __restrict__ g1_w, const float* __restrict__ g1_b,
    const float* __restrict__ g2_w, const float* __restrict__ g2_b,
    float* __restrict__ out)
{
    const int a = blockIdx.x;
    const int tid = threadIdx.x;
    __shared__ __align__(16) float sm[D_M * N_HEADS];   // interp[a][:]
    __shared__ __align__(16) float col[D_M];            // regular[:, a]
    __shared__ __align__(16) float c_s[2 * D_H];
    __shared__ __align__(16) float h_s[D_H];

    {
        const float4* i4 = (const float4*)&interp[a * (D_M * N_HEADS)];
        float4* s4 = (float4*)sm;
        s4[tid & 127] = i4[tid & 127];   // 128 float4 = 512 floats (2x redundant)
    }
    if (tid < D_M) col[tid] = regular[tid * ALPHA + a];
    __syncthreads();

    // e_attn[tid]
    float vattn;
    {
        float pw[N_HEADS];
        const float4* p4 = (const float4*)&proj_w[tid * N_HEADS];
        float4 v0 = p4[0], v1 = p4[1];
        pw[0]=v0.x; pw[1]=v0.y; pw[2]=v0.z; pw[3]=v0.w;
        pw[4]=v1.x; pw[5]=v1.y; pw[6]=v1.z; pw[7]=v1.w;
        float sum = 0.0f;
        #pragma unroll 8
        for (int mm = 0; mm < D_M; mm++) {
            const float4* s4 = (const float4*)&sm[mm * N_HEADS];
            float4 a0 = s4[0], a1 = s4[1];
            sum += a0.x*pw[0] + a0.y*pw[1] + a0.z*pw[2] + a0.w*pw[3]
                 + a1.x*pw[4] + a1.y*pw[5] + a1.z*pw[6] + a1.w*pw[7];
        }
        vattn = proj_b[tid] + sum * (1.0f / 64.0f);
    }
    // e_imp[tid]
    float vimp;
    {
        const float4* row = (const float4*)&conv_w[tid * D_M];
        const float4* c4  = (const float4*)col;
        float s0 = 0.f, s1 = 0.f, s2 = 0.f, s3 = 0.f;
        #pragma unroll
        for (int i = 0; i < D_M / 4; i++) {
            float4 r = row[i]; float4 c = c4[i];
            s0 += r.x * c.x; s1 += r.y * c.y; s2 += r.z * c.z; s3 += r.w * c.w;
        }
        vimp = conv_b[tid] + ((s0 + s1) + (s2 + s3));
    }
    c_s[tid]       = vimp;
    c_s[D_H + tid] = vattn;
    __syncthreads();

    {
        const float4* grow = (const float4*)&g1_w[tid * 2 * D_H];
        const float4* c4 = (const float4*)c_s;
        float s0 = 0.f, s1 = 0.f, s2 = 0.f, s3 = 0.f;
        #pragma unroll 8
        for (int i = 0; i < (2 * D_H) / 4; i++) {
            float4 g = grow[i]; float4 c = c4[i];
            s0 += g.x * c.x; s1 += g.y * c.y; s2 += g.z * c.z; s3 += g.w * c.w;
        }
        float hid = g1_b[tid] + ((s0 + s1) + (s2 + s3));
        h_s[tid] = fmaxf(hid, 0.0f);
    }
    __syncthreads();
    {
        const float4* grow = (const float4*)&g2_w[tid * D_H];
        const float4* h4 = (const float4*)h_s;
        float s0 = 0.f, s1 = 0.f, s2 = 0.f, s3 = 0.f;
        #pragma unroll 8
        for (int i = 0; i < D_H / 4; i++) {
            float4 g = grow[i]; float4 hh = h4[i];
            s0 += g.x * hh.x; s1 += g.y * hh.y; s2 += g.z * hh.z; s3 += g.w * hh.w;
        }
        float z = g2_b[tid] + ((s0 + s1) + (s2 + s3));
        float gate = 1.0f / (1.0f + __expf(-z));
        out[a * D_H + tid] = gate * vimp + (1.0f - gate) * vattn;
    }
}

// ---------------------------------------------------------------------------
extern "C" void kernel_launch(void* const* d_in, const int* in_sizes, int n_in,
                              void* d_out, int out_size, void* d_ws, size_t ws_size,
                              hipStream_t stream)
{
    (void)in_sizes; (void)n_in; (void)out_size; (void)ws_size;

    const float* x_ts    = (const float*)d_in[0];
    const float* t_ts    = (const float*)d_in[1];
    const float* gm      = (const float*)d_in[2];
    const float* conv_w  = (const float*)d_in[3];
    const float* conv_b  = (const float*)d_in[4];
    const float* t2v_w   = (const float*)d_in[5];
    const float* t2v_phi = (const float*)d_in[6];
    const float* wq_w    = (const float*)d_in[7];
    const float* wq_b    = (const float*)d_in[8];
    const float* wk_w    = (const float*)d_in[9];
    const float* wk_b    = (const float*)d_in[10];
    const float* proj_w  = (const float*)d_in[11];
    const float* proj_b  = (const float*)d_in[12];
    const float* g1_w    = (const float*)d_in[13];
    const float* g1_b    = (const float*)d_in[14];
    const float* g2_w    = (const float*)d_in[15];
    const float* g2_b    = (const float*)d_in[16];

    float* out = (float*)d_out;

    float* ws      = (float*)d_ws;
    float* regular = ws;                              // 16384
    float* QbufT   = regular + D_M * ALPHA;           // 131072
    float* interp  = QbufT + N_HEADS * D_V * ALPHA;   // 131072  [a][m][h]

    impute_kernel<<<D_M, 256, 0, stream>>>(x_ts, t_ts, gm, regular);
    qT_kernel<<<dim3(ALPHA, N_HEADS), 64, 0, stream>>>(t2v_w, t2v_phi, wq_w, wq_b, QbufT);
    attn_fused_kernel<<<dim3(D_M / 2, N_HEADS), 512, 0, stream>>>(
        x_ts, t_ts, t2v_w, t2v_phi, wk_w, wk_b, QbufT, interp);
    final_kernel<<<ALPHA, 256, 0, stream>>>(
        regular, interp, conv_w, conv_b, proj_w, proj_b,
        g1_w, g1_b, g2_w, g2_b, out);
}

// Round 4
// 112.297 us; speedup vs baseline: 1.8566x; 1.0356x over previous
//
#include <hip/hip_runtime.h>

#define D_M     64
#define L_OBS   256
#define ALPHA   256
#define D_H     256
#define D_V     64
#define N_HEADS 8

// ---------------------------------------------------------------------------
// Kernel 1: per-row imputation (scatter last-write-wins -> forward fill)
// ---------------------------------------------------------------------------
__global__ __launch_bounds__(256) void impute_kernel(
    const float* __restrict__ x_ts, const float* __restrict__ t_ts,
    const float* __restrict__ gm, float* __restrict__ regular)
{
    const int m = blockIdx.x;
    const int l = threadIdx.x;
    __shared__ int   last[ALPHA];
    __shared__ float vals[ALPHA];
    __shared__ int   pos[ALPHA];

    last[l] = -1;
    __syncthreads();
    float x = x_ts[m * L_OBS + l];
    float t = t_ts[m * L_OBS + l];
    bool valid = (x == x) && (t >= 0.0f);
    int idx = (int)t;
    if (valid && idx < ALPHA) atomicMax(&last[idx], l);
    __syncthreads();
    int li = last[l];
    vals[l] = (li >= 0) ? x_ts[m * L_OBS + li] : 0.0f;
    pos[l]  = (li >= 0) ? l : -1;
    __syncthreads();
    for (int off = 1; off < ALPHA; off <<= 1) {
        int v = (l >= off) ? pos[l - off] : -1;
        __syncthreads();
        if (v > pos[l]) pos[l] = v;
        __syncthreads();
    }
    int lp = pos[l];
    regular[m * ALPHA + l] = (lp >= 0) ? vals[lp] : gm[m];
}

// ---------------------------------------------------------------------------
// Kernel 2: per-h weight folding.
//   WQKT[h][d][d'] = sum_e wq_w[h][e][d'] * wk_w[h][e][d]
//   qwb [h][d]     = sum_e wq_b[h][e]     * wk_w[h][e][d]
//   wqkb[h][d']    = sum_e wq_w[h][e][d'] * wk_b[h][e]
//   c0  [h]        = sum_e wq_b[h][e]     * wk_b[h][e]
// grid (4 seg, 8 h), block 64 (thread = d)
// ---------------------------------------------------------------------------
__global__ __launch_bounds__(64) void wqk_kernel(
    const float* __restrict__ wq_w, const float* __restrict__ wq_b,
    const float* __restrict__ wk_w, const float* __restrict__ wk_b,
    float* __restrict__ WQKT, float* __restrict__ qwb,
    float* __restrict__ wqkb, float* __restrict__ c0)
{
    const int seg = blockIdx.x;
    const int h   = blockIdx.y;
    const int d   = threadIdx.x;

    float acc[16];
    #pragma unroll
    for (int j = 0; j < 16; j++) acc[j] = 0.f;
    float accb = 0.f, accc = 0.f, acc0 = 0.f;

    for (int e = 0; e < D_V; e++) {
        float wkv = wk_w[(h * D_V + e) * D_V + d];
        const float* wqrow = &wq_w[(h * D_V + e) * D_V];
        const float4* wq4 = (const float4*)&wqrow[seg * 16];
        #pragma unroll
        for (int jj = 0; jj < 4; jj++) {
            float4 v = wq4[jj];
            acc[4*jj+0] = fmaf(v.x, wkv, acc[4*jj+0]);
            acc[4*jj+1] = fmaf(v.y, wkv, acc[4*jj+1]);
            acc[4*jj+2] = fmaf(v.z, wkv, acc[4*jj+2]);
            acc[4*jj+3] = fmaf(v.w, wkv, acc[4*jj+3]);
        }
        if (seg == 0) accb = fmaf(wq_b[h * D_V + e], wkv, accb);
        if (seg == 1) accc = fmaf(wqrow[d], wk_b[h * D_V + e], accc);
        if (seg == 2) acc0 = fmaf(wq_b[h * D_V + e], wk_b[h * D_V + e], acc0);
    }
    float* outrow = &WQKT[h * D_V * D_V + d * D_V + seg * 16];
    #pragma unroll
    for (int jj = 0; jj < 4; jj++) {
        float4 o;
        o.x = acc[4*jj+0]; o.y = acc[4*jj+1];
        o.z = acc[4*jj+2]; o.w = acc[4*jj+3];
        *(float4*)&outrow[4*jj] = o;
    }
    if (seg == 0) qwb [h * D_V + d] = accb;
    if (seg == 1) wqkb[h * D_V + d] = accc;
    if (seg == 2 && d == 0) c0[h] = acc0;
}

// ---------------------------------------------------------------------------
// Kernel 3: QW[h][d][a] = sum_d' theta_a[h][a][d'] * WQKT[h][d][d'] + qwb[h][d]
//           qb[h][a]    = sum_d' theta_a[h][a][d'] * wqkb[h][d'] + c0[h]
// grid (ALPHA, 8), block 64 (thread = d)
// ---------------------------------------------------------------------------
__global__ __launch_bounds__(64) void qw_kernel(
    const float* __restrict__ t2v_w, const float* __restrict__ t2v_phi,
    const float* __restrict__ WQKT, const float* __restrict__ qwb,
    const float* __restrict__ wqkb, const float* __restrict__ c0,
    float* __restrict__ QWbuf, float* __restrict__ qb)
{
    const int a = blockIdx.x;
    const int h = blockIdx.y;
    const int d = threadIdx.x;
    __shared__ float th[D_V];
    float f = t2v_w[h * D_V + d] * (float)a + t2v_phi[h * D_V + d];
    float thd = (d == 0) ? f : __sinf(f);
    th[d] = thd;
    __syncthreads();

    float acc = qwb[h * D_V + d];
    const float4* wr = (const float4*)&WQKT[h * D_V * D_V + d * D_V];
    const float4* t4 = (const float4*)th;
    #pragma unroll
    for (int j = 0; j < 16; j++) {
        float4 w = wr[j]; float4 t = t4[j];
        acc += w.x * t.x + w.y * t.y + w.z * t.z + w.w * t.w;
    }
    QWbuf[h * D_V * ALPHA + d * ALPHA + a] = acc;

    float partial = thd * wqkb[h * D_V + d];
    partial += __shfl_xor(partial, 1);
    partial += __shfl_xor(partial, 2);
    partial += __shfl_xor(partial, 4);
    partial += __shfl_xor(partial, 8);
    partial += __shfl_xor(partial, 16);
    partial += __shfl_xor(partial, 32);
    if (d == 0) qb[h * ALPHA + a] = partial + c0[h];
}

// ---------------------------------------------------------------------------
// Kernel 4: fused mTAND attention (K-projection algebraically eliminated).
// Block 512 = 2 m-halves x 256, grid (32, 8) = 256 blocks = 1/CU.
// S[a][l] = sum_d QW[d][a] * theta_o[d][l] + qb[a]   (then *0.125, mask)
// Per 128-l supertile: P1 theta -> LDS; P3 8a x 16l register tile per thread
// (6 ds_read_b128 per 128 FMA, all <=2-way bank patterns); online softmax.
// LDS: QWs 64K + tht 64K + obs 6K + qbs/t2v 1.5K = 139 KiB.
// ---------------------------------------------------------------------------
__global__ __launch_bounds__(512, 2) void attn_fused_kernel(
    const float* __restrict__ x_ts, const float* __restrict__ t_ts,
    const float* __restrict__ t2v_w, const float* __restrict__ t2v_phi,
    const float* __restrict__ QWbuf, const float* __restrict__ qb,
    float* __restrict__ interp)
{
    const int mp  = blockIdx.x;
    const int h   = blockIdx.y;
    const int tid = threadIdx.x;    // 0..511
    const int hm  = tid >> 8;
    const int t2  = tid & 255;
    const int m   = mp * 2 + hm;

    __shared__ __align__(16) float QWs[D_V][ALPHA];    // 64 KiB [d][a]
    __shared__ __align__(16) float tht[2][D_V][128];   // 64 KiB [hm][d][l]
    __shared__ float qbs[ALPHA];                       // 1 KiB
    __shared__ float t2vw_s[D_V], t2vp_s[D_V];
    __shared__ float x_s[2][L_OBS];
    __shared__ float t_sh[2][L_OBS];
    __shared__ float msk_s[2][L_OBS];

    // ---- stage obs row for this half's m ----
    {
        float x = x_ts[m * L_OBS + t2];
        float t = t_ts[m * L_OBS + t2];
        bool v = (x == x) && (t >= 0.0f);
        x_s[hm][t2]   = v ? x : 0.0f;
        t_sh[hm][t2]  = v ? t : 0.0f;
        msk_s[hm][t2] = v ? 0.0f : -1e9f;
    }
    // ---- stage QW row [d][a] (4096 float4) ----
    {
        const float4* q4 = (const float4*)(QWbuf + h * D_V * ALPHA);
        float4* qs4 = (float4*)&QWs[0][0];
        #pragma unroll
        for (int i = 0; i < 8; i++)
            qs4[i * 512 + tid] = q4[i * 512 + tid];
    }
    if (tid < ALPHA) qbs[tid] = qb[h * ALPHA + tid];
    if (tid >= ALPHA && tid < ALPHA + D_V) t2vw_s[tid - ALPHA] = t2v_w[h * D_V + tid - ALPHA];
    if (tid >= ALPHA + D_V && tid < ALPHA + 2 * D_V)
        t2vp_s[tid - ALPHA - D_V] = t2v_phi[h * D_V + tid - ALPHA - D_V];

    const int ta = t2 >> 3;   // 32 groups x 8 a
    const int tl = t2 & 7;    // 8 groups x 16 l (strided: l = tl*4 + k*32)

    float mrun[8], ssum[8], axs[8];
    #pragma unroll
    for (int i = 0; i < 8; i++) { mrun[i] = -3.0e38f; ssum[i] = 0.f; axs[i] = 0.f; }

    // qb row values for this thread's 8 a-rows (read after staging barrier)
    __syncthreads();

    float qbv[8];
    {
        const float4* qb4 = (const float4*)&qbs[ta * 8];
        float4 v0 = qb4[0], v1 = qb4[1];
        qbv[0]=v0.x; qbv[1]=v0.y; qbv[2]=v0.z; qbv[3]=v0.w;
        qbv[4]=v1.x; qbv[5]=v1.y; qbv[6]=v1.z; qbv[7]=v1.w;
    }

    const float4* QW4 = (const float4*)&QWs[0][0];          // row d: 64 float4
    const float4* TH4 = (const float4*)&tht[hm][0][0];      // row d: 32 float4
    const float4* XS4 = (const float4*)&x_s[hm][0];
    const float4* MS4 = (const float4*)&msk_s[hm][0];

    for (int st = 0; st < 2; st++) {
        // ---- P1: theta for 128 l (this half's m) ----
        {
            int lloc = t2 & 127;
            int dbase = (t2 >> 7) * 32;
            float tval = t_sh[hm][st * 128 + lloc];
            #pragma unroll
            for (int dd = 0; dd < 32; dd++) {
                int d = dbase + dd;
                float f = t2vw_s[d] * tval + t2vp_s[d];
                tht[hm][d][lloc] = (d == 0) ? f : __sinf(f);
            }
        }
        __syncthreads();
        // ---- P3: 8a x 16l accumulate over d (acc init = qb[a]) ----
        float acc[8][16];
        #pragma unroll
        for (int i = 0; i < 8; i++)
            #pragma unroll
            for (int j = 0; j < 16; j++) acc[i][j] = qbv[i];
        #pragma unroll 2
        for (int d = 0; d < D_V; d++) {
            float4 q0 = QW4[d * 64 + ta * 2];
            float4 q1 = QW4[d * 64 + ta * 2 + 1];
            float qa[8] = {q0.x, q0.y, q0.z, q0.w, q1.x, q1.y, q1.z, q1.w};
            float4 t0 = TH4[d * 32 + tl];
            float4 t1 = TH4[d * 32 + tl + 8];
            float4 t2v = TH4[d * 32 + tl + 16];
            float4 t3 = TH4[d * 32 + tl + 24];
            float tb[16] = {t0.x,t0.y,t0.z,t0.w, t1.x,t1.y,t1.z,t1.w,
                            t2v.x,t2v.y,t2v.z,t2v.w, t3.x,t3.y,t3.z,t3.w};
            #pragma unroll
            for (int i = 0; i < 8; i++)
                #pragma unroll
                for (int j = 0; j < 16; j++)
                    acc[i][j] = fmaf(qa[i], tb[j], acc[i][j]);
        }
        // ---- online softmax update (l = st*128 + tl*4 + k*32 + jj) ----
        float xv[16], mk[16];
        #pragma unroll
        for (int k = 0; k < 4; k++) {
            float4 xk = XS4[st * 32 + tl + k * 8];
            float4 mkk = MS4[st * 32 + tl + k * 8];
            xv[k*4+0]=xk.x; xv[k*4+1]=xk.y; xv[k*4+2]=xk.z; xv[k*4+3]=xk.w;
            mk[k*4+0]=mkk.x; mk[k*4+1]=mkk.y; mk[k*4+2]=mkk.z; mk[k*4+3]=mkk.w;
        }
        #pragma unroll
        for (int i = 0; i < 8; i++) {
            float s[16];
            #pragma unroll
            for (int j = 0; j < 16; j++) s[j] = fmaf(acc[i][j], 0.125f, mk[j]);
            float tmax = s[0];
            #pragma unroll
            for (int j = 1; j < 16; j++) tmax = fmaxf(tmax, s[j]);
            tmax = fmaxf(tmax, __shfl_xor(tmax, 1));
            tmax = fmaxf(tmax, __shfl_xor(tmax, 2));
            tmax = fmaxf(tmax, __shfl_xor(tmax, 4));
            float mnew = fmaxf(mrun[i], tmax);
            float scl = __expf(mrun[i] - mnew);
            float ps = 0.f, px = 0.f;
            #pragma unroll
            for (int j = 0; j < 16; j++) {
                float p = __expf(s[j] - mnew);
                ps += p;
                px = fmaf(p, xv[j], px);
            }
            ps += __shfl_xor(ps, 1); px += __shfl_xor(px, 1);
            ps += __shfl_xor(ps, 2); px += __shfl_xor(px, 2);
            ps += __shfl_xor(ps, 4); px += __shfl_xor(px, 4);
            ssum[i] = fmaf(ssum[i], scl, ps);
            axs[i]  = fmaf(axs[i],  scl, px);
            mrun[i] = mnew;
        }
        if (st == 0) __syncthreads();  // tht overwrite guard
    }

    // interp layout [a][m][h]
    if (tl == 0) {
        #pragma unroll
        for (int i = 0; i < 8; i++)
            interp[(ta * 8 + i) * (D_M * N_HEADS) + m * N_HEADS + h] =
                axs[i] / ssum[i];
    }
}

// ---------------------------------------------------------------------------
// Kernel 5: fused e_imp + e_attn + gate MLP + output. Block per a, 256 thr.
// ---------------------------------------------------------------------------
__global__ __launch_bounds__(256) void final_kernel(
    const float* __restrict__ regular, const float* __restrict__ interp,
    const float* __restrict__ conv_w, const float* __restrict__ conv_b,
    const float* __restrict__ proj_w, const float* __restrict__ proj_b,
    const float* __restrict__ g1_w, const float* __restrict__ g1_b,
    const float* __restrict__ g2_w, const float* __restrict__ g2_b,
    float* __restrict__ out)
{
    const int a = blockIdx.x;
    const int tid = threadIdx.x;
    __shared__ __align__(16) float sm[D_M * N_HEADS];
    __shared__ __align__(16) float col[D_M];
    __shared__ __align__(16) float c_s[2 * D_H];
    __shared__ __align__(16) float h_s[D_H];

    {
        const float4* i4 = (const float4*)&interp[a * (D_M * N_HEADS)];
        float4* s4 = (float4*)sm;
        s4[tid & 127] = i4[tid & 127];
    }
    if (tid < D_M) col[tid] = regular[tid * ALPHA + a];
    __syncthreads();

    float vattn;
    {
        float pw[N_HEADS];
        const float4* p4 = (const float4*)&proj_w[tid * N_HEADS];
        float4 v0 = p4[0], v1 = p4[1];
        pw[0]=v0.x; pw[1]=v0.y; pw[2]=v0.z; pw[3]=v0.w;
        pw[4]=v1.x; pw[5]=v1.y; pw[6]=v1.z; pw[7]=v1.w;
        float sum = 0.0f;
        #pragma unroll 8
        for (int mm = 0; mm < D_M; mm++) {
            const float4* s4 = (const float4*)&sm[mm * N_HEADS];
            float4 a0 = s4[0], a1 = s4[1];
            sum += a0.x*pw[0] + a0.y*pw[1] + a0.z*pw[2] + a0.w*pw[3]
                 + a1.x*pw[4] + a1.y*pw[5] + a1.z*pw[6] + a1.w*pw[7];
        }
        vattn = proj_b[tid] + sum * (1.0f / 64.0f);
    }
    float vimp;
    {
        const float4* row = (const float4*)&conv_w[tid * D_M];
        const float4* c4  = (const float4*)col;
        float s0 = 0.f, s1 = 0.f, s2 = 0.f, s3 = 0.f;
        #pragma unroll
        for (int i = 0; i < D_M / 4; i++) {
            float4 r = row[i]; float4 c = c4[i];
            s0 += r.x * c.x; s1 += r.y * c.y; s2 += r.z * c.z; s3 += r.w * c.w;
        }
        vimp = conv_b[tid] + ((s0 + s1) + (s2 + s3));
    }
    c_s[tid]       = vimp;
    c_s[D_H + tid] = vattn;
    __syncthreads();

    {
        const float4* grow = (const float4*)&g1_w[tid * 2 * D_H];
        const float4* c4 = (const float4*)c_s;
        float s0 = 0.f, s1 = 0.f, s2 = 0.f, s3 = 0.f;
        #pragma unroll 8
        for (int i = 0; i < (2 * D_H) / 4; i++) {
            float4 g = grow[i]; float4 c = c4[i];
            s0 += g.x * c.x; s1 += g.y * c.y; s2 += g.z * c.z; s3 += g.w * c.w;
        }
        float hid = g1_b[tid] + ((s0 + s1) + (s2 + s3));
        h_s[tid] = fmaxf(hid, 0.0f);
    }
    __syncthreads();
    {
        const float4* grow = (const float4*)&g2_w[tid * D_H];
        const float4* h4 = (const float4*)h_s;
        float s0 = 0.f, s1 = 0.f, s2 = 0.f, s3 = 0.f;
        #pragma unroll 8
        for (int i = 0; i < D_H / 4; i++) {
            float4 g = grow[i]; float4 hh = h4[i];
            s0 += g.x * hh.x; s1 += g.y * hh.y; s2 += g.z * hh.z; s3 += g.w * hh.w;
        }
        float z = g2_b[tid] + ((s0 + s1) + (s2 + s3));
        float gate = 1.0f / (1.0f + __expf(-z));
        out[a * D_H + tid] = gate * vimp + (1.0f - gate) * vattn;
    }
}

// ---------------------------------------------------------------------------
extern "C" void kernel_launch(void* const* d_in, const int* in_sizes, int n_in,
                              void* d_out, int out_size, void* d_ws, size_t ws_size,
                              hipStream_t stream)
{
    (void)in_sizes; (void)n_in; (void)out_size; (void)ws_size;

    const float* x_ts    = (const float*)d_in[0];
    const float* t_ts    = (const float*)d_in[1];
    const float* gm      = (const float*)d_in[2];
    const float* conv_w  = (const float*)d_in[3];
    const float* conv_b  = (const float*)d_in[4];
    const float* t2v_w   = (const float*)d_in[5];
    const float* t2v_phi = (const float*)d_in[6];
    const float* wq_w    = (const float*)d_in[7];
    const float* wq_b    = (const float*)d_in[8];
    const float* wk_w    = (const float*)d_in[9];
    const float* wk_b    = (const float*)d_in[10];
    const float* proj_w  = (const float*)d_in[11];
    const float* proj_b  = (const float*)d_in[12];
    const float* g1_w    = (const float*)d_in[13];
    const float* g1_b    = (const float*)d_in[14];
    const float* g2_w    = (const float*)d_in[15];
    const float* g2_b    = (const float*)d_in[16];

    float* out = (float*)d_out;

    float* ws      = (float*)d_ws;
    float* regular = ws;                               // 16384
    float* WQKT    = regular + D_M * ALPHA;            // 32768
    float* qwb     = WQKT + N_HEADS * D_V * D_V;       // 512
    float* wqkb    = qwb + N_HEADS * D_V;              // 512
    float* c0      = wqkb + N_HEADS * D_V;             // 8
    float* qb      = c0 + N_HEADS;                     // 2048
    float* QWbuf   = qb + N_HEADS * ALPHA;             // 131072
    float* interp  = QWbuf + N_HEADS * D_V * ALPHA;    // 131072

    impute_kernel<<<D_M, 256, 0, stream>>>(x_ts, t_ts, gm, regular);
    wqk_kernel<<<dim3(4, N_HEADS), 64, 0, stream>>>(
        wq_w, wq_b, wk_w, wk_b, WQKT, qwb, wqkb, c0);
    qw_kernel<<<dim3(ALPHA, N_HEADS), 64, 0, stream>>>(
        t2v_w, t2v_phi, WQKT, qwb, wqkb, c0, QWbuf, qb);
    attn_fused_kernel<<<dim3(D_M / 2, N_HEADS), 512, 0, stream>>>(
        x_ts, t_ts, t2v_w, t2v_phi, QWbuf, qb, interp);
    final_kernel<<<ALPHA, 256, 0, stream>>>(
        regular, interp, conv_w, conv_b, proj_w, proj_b,
        g1_w, g1_b, g2_w, g2_b, out);
}

// Round 5
// 91.606 us; speedup vs baseline: 2.2760x; 1.2259x over previous
//
#include <hip/hip_runtime.h>

#define D_M     64
#define L_OBS   256
#define ALPHA   256
#define D_H     256
#define D_V     64
#define N_HEADS 8

// ---------------------------------------------------------------------------
// Kernel 1: prep. Blocks 0..63: per-row imputation. Blocks 64..191: per-(h,
// 16-a-chunk) fold: Qa = theta_a . wq^T + wq_b, then QW[d][a] = Qa . wk[.][d].
// (All a-row-constant score terms are dropped: softmax is shift-invariant.)
// ---------------------------------------------------------------------------
__global__ __launch_bounds__(256) void prep_kernel(
    const float* __restrict__ x_ts, const float* __restrict__ t_ts,
    const float* __restrict__ gm,
    const float* __restrict__ t2v_w, const float* __restrict__ t2v_phi,
    const float* __restrict__ wq_w, const float* __restrict__ wq_b,
    const float* __restrict__ wk_w,
    float* __restrict__ regular, float* __restrict__ QWbuf)
{
    const int tid = threadIdx.x;

    // impute branch LDS
    __shared__ int   last[ALPHA];
    __shared__ float vals[ALPHA];
    __shared__ int   pos[ALPHA];
    // fold branch LDS (padded to 68 to break stride-64 bank patterns)
    __shared__ __align__(16) float wq_s[D_V][68];
    __shared__ __align__(16) float thA[16][68];
    __shared__ __align__(16) float QaT[16][68];

    if (blockIdx.x < D_M) {
        // ---------------- imputation ----------------
        const int m = blockIdx.x;
        const int l = tid;
        last[l] = -1;
        __syncthreads();
        float x = x_ts[m * L_OBS + l];
        float t = t_ts[m * L_OBS + l];
        bool valid = (x == x) && (t >= 0.0f);
        int idx = (int)t;
        if (valid && idx < ALPHA) atomicMax(&last[idx], l);
        __syncthreads();
        int li = last[l];
        vals[l] = (li >= 0) ? x_ts[m * L_OBS + li] : 0.0f;
        pos[l]  = (li >= 0) ? l : -1;
        __syncthreads();
        for (int off = 1; off < ALPHA; off <<= 1) {
            int v = (l >= off) ? pos[l - off] : -1;
            __syncthreads();
            if (v > pos[l]) pos[l] = v;
            __syncthreads();
        }
        int lp = pos[l];
        regular[m * ALPHA + l] = (lp >= 0) ? vals[lp] : gm[m];
    } else {
        // ---------------- weight fold + QW for 16 a ----------------
        const int p  = blockIdx.x - D_M;   // 0..127
        const int h  = p >> 4;
        const int a0 = (p & 15) * 16;

        // stage wq_s[e][d'] (padded rows)
        {
            const float4* w4 = (const float4*)(wq_w + h * D_V * D_V);
            #pragma unroll
            for (int i = 0; i < 4; i++) {
                int f = i * 256 + tid;
                float4 v = w4[f];
                int e = f >> 4, c = (f & 15) * 4;
                *(float4*)&wq_s[e][c] = v;
            }
        }
        // theta_a for 16 a's: 4 values per thread
        {
            int al = tid >> 4, j0 = (tid & 15) * 4;
            float tv = (float)(a0 + al);
            #pragma unroll
            for (int j = 0; j < 4; j++) {
                int d = j0 + j;
                float f = t2v_w[h * D_V + d] * tv + t2v_phi[h * D_V + d];
                thA[al][d] = (d == 0) ? f : __sinf(f);
            }
        }
        __syncthreads();

        // Phase A: QaT[a][e] = thA[a] . wq_s[e] + wq_b[e]
        {
            const int e  = tid >> 2;
            const int ap = tid & 3;
            float accA[4] = {0.f, 0.f, 0.f, 0.f};
            const float4* wrow = (const float4*)&wq_s[e][0];
            #pragma unroll
            for (int j = 0; j < 16; j++) {
                float4 w = wrow[j];
                #pragma unroll
                for (int k = 0; k < 4; k++) {
                    float4 tv = *(const float4*)&thA[ap + 4 * k][j * 4];
                    accA[k] += w.x * tv.x + w.y * tv.y + w.z * tv.z + w.w * tv.w;
                }
            }
            float bq = wq_b[h * D_V + e];
            #pragma unroll
            for (int k = 0; k < 4; k++) QaT[ap + 4 * k][e] = accA[k] + bq;
        }
        __syncthreads();

        // Phase B: QW[d][a] = sum_e QaT[a][e] * wk_w[h][e][d]
        {
            const int d  = tid >> 2;
            const int ap = tid & 3;
            float accB[4] = {0.f, 0.f, 0.f, 0.f};
            #pragma unroll 4
            for (int e4 = 0; e4 < 16; e4++) {
                const float* wkp = &wk_w[(h * D_V + e4 * 4) * D_V + d];
                float w0 = wkp[0];
                float w1 = wkp[D_V];
                float w2 = wkp[2 * D_V];
                float w3 = wkp[3 * D_V];
                #pragma unroll
                for (int k = 0; k < 4; k++) {
                    float4 qv = *(const float4*)&QaT[ap + 4 * k][e4 * 4];
                    accB[k] += qv.x * w0 + qv.y * w1 + qv.z * w2 + qv.w * w3;
                }
            }
            #pragma unroll
            for (int k = 0; k < 4; k++)
                QWbuf[h * D_V * ALPHA + d * ALPHA + a0 + ap + 4 * k] = accB[k];
        }
    }
}

// ---------------------------------------------------------------------------
// Kernel 2: fused mTAND attention. Block 256 thr per (m, h), grid (64, 8)
// = 512 blocks = 2 per CU. QW read from GLOBAL (L2, VMEM pipe); theta from
// LDS (computed in-kernel). 8a x 16l register tile (6 loads / 128 FMA, split
// 2 VMEM + 4 LDS across independent pipes). Lane-local online softmax in
// exp2 domain; single cross-lane merge at the end.
// LDS: tht 32K + obs 3K + t2v 0.5K ~= 36 KiB.
// ---------------------------------------------------------------------------
__global__ __launch_bounds__(256, 2) void attn_fused_kernel(
    const float* __restrict__ x_ts, const float* __restrict__ t_ts,
    const float* __restrict__ t2v_w, const float* __restrict__ t2v_phi,
    const float* __restrict__ QWbuf, float* __restrict__ interp)
{
    const int m   = blockIdx.x;
    const int h   = blockIdx.y;
    const int tid = threadIdx.x;

    __shared__ __align__(16) float tht[D_V][128];   // 32 KiB [d][l]
    __shared__ float t2vw_s[D_V], t2vp_s[D_V];
    __shared__ float x_s[L_OBS], t_sh[L_OBS], msk_s[L_OBS];

    {
        float x = x_ts[m * L_OBS + tid];
        float t = t_ts[m * L_OBS + tid];
        bool v = (x == x) && (t >= 0.0f);
        x_s[tid]   = v ? x : 0.0f;
        t_sh[tid]  = v ? t : 0.0f;
        msk_s[tid] = v ? 0.0f : -1e9f;
    }
    if (tid < D_V) t2vw_s[tid] = t2v_w[h * D_V + tid];
    else if (tid < 2 * D_V) t2vp_s[tid - D_V] = t2v_phi[h * D_V + tid - D_V];

    const int ta = tid >> 3;   // 32 groups x 8 a
    const int tl = tid & 7;    // 8 groups x 16 l (l = st*128 + tl*4 + k*32 + jj)
    const float SCALE2 = 0.18033688011112042f;  // 0.125 * log2(e)

    const float4* QW4 = (const float4*)(QWbuf + h * D_V * ALPHA);
    const float4* TH4 = (const float4*)&tht[0][0];
    const float4* XS4 = (const float4*)x_s;
    const float4* MS4 = (const float4*)msk_s;

    float mrun[8], ssum[8], axs[8];
    #pragma unroll
    for (int i = 0; i < 8; i++) { mrun[i] = -3.0e38f; ssum[i] = 0.f; axs[i] = 0.f; }

    __syncthreads();

    for (int st = 0; st < 2; st++) {
        // ---- P1: theta for 128 l ----
        {
            int lloc = tid & 127;
            int dbase = (tid >> 7) * 32;
            float tval = t_sh[st * 128 + lloc];
            #pragma unroll
            for (int dd = 0; dd < 32; dd++) {
                int d = dbase + dd;
                float f = t2vw_s[d] * tval + t2vp_s[d];
                tht[d][lloc] = (d == 0) ? f : __sinf(f);
            }
        }
        __syncthreads();
        // ---- P3: 8a x 16l over d; QW from global (VMEM), theta from LDS ----
        float acc[8][16];
        #pragma unroll
        for (int i = 0; i < 8; i++)
            #pragma unroll
            for (int j = 0; j < 16; j++) acc[i][j] = 0.f;
        #pragma unroll 2
        for (int d = 0; d < D_V; d++) {
            float4 q0 = QW4[d * 64 + ta * 2];
            float4 q1 = QW4[d * 64 + ta * 2 + 1];
            float qa[8] = {q0.x, q0.y, q0.z, q0.w, q1.x, q1.y, q1.z, q1.w};
            float4 t0 = TH4[d * 32 + tl];
            float4 t1 = TH4[d * 32 + tl + 8];
            float4 t2 = TH4[d * 32 + tl + 16];
            float4 t3 = TH4[d * 32 + tl + 24];
            float tb[16] = {t0.x,t0.y,t0.z,t0.w, t1.x,t1.y,t1.z,t1.w,
                            t2.x,t2.y,t2.z,t2.w, t3.x,t3.y,t3.z,t3.w};
            #pragma unroll
            for (int i = 0; i < 8; i++)
                #pragma unroll
                for (int j = 0; j < 16; j++)
                    acc[i][j] = fmaf(qa[i], tb[j], acc[i][j]);
        }
        // ---- lane-local online softmax update (base-2 domain) ----
        float xv[16], mk[16];
        #pragma unroll
        for (int k = 0; k < 4; k++) {
            float4 xk  = XS4[st * 32 + tl + k * 8];
            float4 mkk = MS4[st * 32 + tl + k * 8];
            xv[k*4+0]=xk.x; xv[k*4+1]=xk.y; xv[k*4+2]=xk.z; xv[k*4+3]=xk.w;
            mk[k*4+0]=mkk.x; mk[k*4+1]=mkk.y; mk[k*4+2]=mkk.z; mk[k*4+3]=mkk.w;
        }
        #pragma unroll
        for (int i = 0; i < 8; i++) {
            float s[16];
            #pragma unroll
            for (int j = 0; j < 16; j++) s[j] = fmaf(acc[i][j], SCALE2, mk[j]);
            float tmax = s[0];
            #pragma unroll
            for (int j = 1; j < 16; j++) tmax = fmaxf(tmax, s[j]);
            float mnew = fmaxf(mrun[i], tmax);
            float scl = __builtin_amdgcn_exp2f(mrun[i] - mnew);
            float ps = 0.f, px = 0.f;
            #pragma unroll
            for (int j = 0; j < 16; j++) {
                float pv = __builtin_amdgcn_exp2f(s[j] - mnew);
                ps += pv;
                px = fmaf(pv, xv[j], px);
            }
            ssum[i] = fmaf(ssum[i], scl, ps);
            axs[i]  = fmaf(axs[i],  scl, px);
            mrun[i] = mnew;
        }
        if (st == 0) __syncthreads();  // tht overwrite guard
    }

    // ---- merge across the 8 tl lanes, write interp [a][m][h] ----
    #pragma unroll
    for (int i = 0; i < 8; i++) {
        float m0 = mrun[i];
        m0 = fmaxf(m0, __shfl_xor(m0, 1));
        m0 = fmaxf(m0, __shfl_xor(m0, 2));
        m0 = fmaxf(m0, __shfl_xor(m0, 4));
        float f = __builtin_amdgcn_exp2f(mrun[i] - m0);
        float S = ssum[i] * f;
        float A = axs[i] * f;
        S += __shfl_xor(S, 1); A += __shfl_xor(A, 1);
        S += __shfl_xor(S, 2); A += __shfl_xor(A, 2);
        S += __shfl_xor(S, 4); A += __shfl_xor(A, 4);
        if (tl == 0)
            interp[(ta * 8 + i) * (D_M * N_HEADS) + m * N_HEADS + h] = A / S;
    }
}

// ---------------------------------------------------------------------------
// Kernel 3: fused e_imp + e_attn + gate MLP + output. Block per a, 256 thr.
// e_attn uses isum[h] = sum_m interp[a][m][h] (wave-0 butterfly) -> 8-dot.
// ---------------------------------------------------------------------------
__global__ __launch_bounds__(256) void final_kernel(
    const float* __restrict__ regular, const float* __restrict__ interp,
    const float* __restrict__ conv_w, const float* __restrict__ conv_b,
    const float* __restrict__ proj_w, const float* __restrict__ proj_b,
    const float* __restrict__ g1_w, const float* __restrict__ g1_b,
    const float* __restrict__ g2_w, const float* __restrict__ g2_b,
    float* __restrict__ out)
{
    const int a = blockIdx.x;
    const int tid = threadIdx.x;
    __shared__ float isum_s[N_HEADS];
    __shared__ __align__(16) float col[D_M];
    __shared__ __align__(16) float c_s[2 * D_H];
    __shared__ __align__(16) float h_s[D_H];

    if (tid < 64) {
        const float4* i4 = (const float4*)&interp[a * (D_M * N_HEADS) + tid * 8];
        float4 v0 = i4[0], v1 = i4[1];
        float v[8] = {v0.x, v0.y, v0.z, v0.w, v1.x, v1.y, v1.z, v1.w};
        #pragma unroll
        for (int s = 1; s < 64; s <<= 1) {
            #pragma unroll
            for (int j = 0; j < 8; j++) v[j] += __shfl_xor(v[j], s);
        }
        if (tid == 0) {
            #pragma unroll
            for (int j = 0; j < 8; j++) isum_s[j] = v[j];
        }
    } else if (tid < 128) {
        col[tid - 64] = regular[(tid - 64) * ALPHA + a];
    }
    __syncthreads();

    // e_attn[tid]
    float vattn;
    {
        const float4* p4 = (const float4*)&proj_w[tid * N_HEADS];
        float4 v0 = p4[0], v1 = p4[1];
        float sum = v0.x * isum_s[0] + v0.y * isum_s[1] + v0.z * isum_s[2]
                  + v0.w * isum_s[3] + v1.x * isum_s[4] + v1.y * isum_s[5]
                  + v1.z * isum_s[6] + v1.w * isum_s[7];
        vattn = proj_b[tid] + sum * (1.0f / 64.0f);
    }
    // e_imp[tid]
    float vimp;
    {
        const float4* row = (const float4*)&conv_w[tid * D_M];
        const float4* c4  = (const float4*)col;
        float s0 = 0.f, s1 = 0.f, s2 = 0.f, s3 = 0.f;
        #pragma unroll
        for (int i = 0; i < D_M / 4; i++) {
            float4 r = row[i]; float4 c = c4[i];
            s0 += r.x * c.x; s1 += r.y * c.y; s2 += r.z * c.z; s3 += r.w * c.w;
        }
        vimp = conv_b[tid] + ((s0 + s1) + (s2 + s3));
    }
    c_s[tid]       = vimp;
    c_s[D_H + tid] = vattn;
    __syncthreads();

    {
        const float4* grow = (const float4*)&g1_w[tid * 2 * D_H];
        const float4* c4 = (const float4*)c_s;
        float s0 = 0.f, s1 = 0.f, s2 = 0.f, s3 = 0.f;
        #pragma unroll 8
        for (int i = 0; i < (2 * D_H) / 4; i++) {
            float4 g = grow[i]; float4 c = c4[i];
            s0 += g.x * c.x; s1 += g.y * c.y; s2 += g.z * c.z; s3 += g.w * c.w;
        }
        float hid = g1_b[tid] + ((s0 + s1) + (s2 + s3));
        h_s[tid] = fmaxf(hid, 0.0f);
    }
    __syncthreads();
    {
        const float4* grow = (const float4*)&g2_w[tid * D_H];
        const float4* h4 = (const float4*)h_s;
        float s0 = 0.f, s1 = 0.f, s2 = 0.f, s3 = 0.f;
        #pragma unroll 8
        for (int i = 0; i < D_H / 4; i++) {
            float4 g = grow[i]; float4 hh = h4[i];
            s0 += g.x * hh.x; s1 += g.y * hh.y; s2 += g.z * hh.z; s3 += g.w * hh.w;
        }
        float z = g2_b[tid] + ((s0 + s1) + (s2 + s3));
        float gate = 1.0f / (1.0f + __expf(-z));
        out[a * D_H + tid] = gate * vimp + (1.0f - gate) * vattn;
    }
}

// ---------------------------------------------------------------------------
extern "C" void kernel_launch(void* const* d_in, const int* in_sizes, int n_in,
                              void* d_out, int out_size, void* d_ws, size_t ws_size,
                              hipStream_t stream)
{
    (void)in_sizes; (void)n_in; (void)out_size; (void)ws_size;

    const float* x_ts    = (const float*)d_in[0];
    const float* t_ts    = (const float*)d_in[1];
    const float* gm      = (const float*)d_in[2];
    const float* conv_w  = (const float*)d_in[3];
    const float* conv_b  = (const float*)d_in[4];
    const float* t2v_w   = (const float*)d_in[5];
    const float* t2v_phi = (const float*)d_in[6];
    const float* wq_w    = (const float*)d_in[7];
    const float* wq_b    = (const float*)d_in[8];
    const float* wk_w    = (const float*)d_in[9];
    const float* proj_w  = (const float*)d_in[11];
    const float* proj_b  = (const float*)d_in[12];
    const float* g1_w    = (const float*)d_in[13];
    const float* g1_b    = (const float*)d_in[14];
    const float* g2_w    = (const float*)d_in[15];
    const float* g2_b    = (const float*)d_in[16];

    float* out = (float*)d_out;

    float* ws      = (float*)d_ws;
    float* regular = ws;                               // 16384
    float* QWbuf   = regular + D_M * ALPHA;            // 131072  [h][d][a]
    float* interp  = QWbuf + N_HEADS * D_V * ALPHA;    // 131072  [a][m][h]

    prep_kernel<<<D_M + 128, 256, 0, stream>>>(
        x_ts, t_ts, gm, t2v_w, t2v_phi, wq_w, wq_b, wk_w, regular, QWbuf);
    attn_fused_kernel<<<dim3(D_M, N_HEADS), 256, 0, stream>>>(
        x_ts, t_ts, t2v_w, t2v_phi, QWbuf, interp);
    final_kernel<<<ALPHA, 256, 0, stream>>>(
        regular, interp, conv_w, conv_b, proj_w, proj_b,
        g1_w, g1_b, g2_w, g2_b, out);
}